// Round 11
// baseline (106.890 us; speedup 1.0000x reference)
//
#include <hip/hip_runtime.h>

#define KI 32
#define BG_SAMPLE 100
#define EPAD 272   // s_embh row stride in halves (256 + 16 pad)

// ws float layout (per batch b at b*224):
//   acc[224] = { cnt[32], cntk[32], sums d-major [4][32], valsum[32] }
// misc[B][4] = {sum_pair,l_reg,sum_bg,pad} at B*224+B*128 + b*4.
// total B*356 floats.

typedef __attribute__((ext_vector_type(8))) _Float16 half8;
typedef __attribute__((ext_vector_type(4))) float f32x4;
typedef __attribute__((ext_vector_type(4))) int i32x4;
typedef union { unsigned u[4]; half8 v; } hfrag;

static __device__ __forceinline__ unsigned pkrtz(float a, float b) {
  unsigned d;
  asm("v_cvt_pkrtz_f16_f32 %0, %1, %2" : "=v"(d) : "v"(a), "v"(b));
  return d;
}
static __device__ __forceinline__ unsigned ohpair16(int la, int lb_, int r) {
  return ((la == r) ? 0x3C00u : 0u) | ((lb_ == r) ? 0x3C000000u : 0u);
}
static __device__ __forceinline__ float waveReduceSum(float v) {
#pragma unroll
  for (int off = 32; off > 0; off >>= 1) v += __shfl_down(v, off, 64);
  return v;
}

struct Tile { i32x4 L; f32x4 T, Kk, E0, E1, E2, E3; };

static __device__ __forceinline__ void load_tile(Tile& R, const int* instb,
    const float* kernb, const float* tmb, const float* embb, int N, int p0)
{
  R.L  = *(const i32x4*)(instb + p0);
  R.T  = *(const f32x4*)(tmb + p0);
  R.Kk = __builtin_nontemporal_load((const f32x4*)(kernb + p0));  // single-use
  R.E0 = *(const f32x4*)(embb + p0);
  R.E1 = *(const f32x4*)(embb + (size_t)N + p0);
  R.E2 = *(const f32x4*)(embb + (size_t)2 * N + p0);
  R.E3 = *(const f32x4*)(embb + (size_t)3 * N + p0);
}

// -------- pass1: MFMA one-hot, 3-deep register prefetch, 128-VGPR budget ---
__global__ __launch_bounds__(256, 4)
void pass1_kernel(const float* __restrict__ emb, const int* __restrict__ inst,
                  const float* __restrict__ kern, const float* __restrict__ tmask,
                  float* __restrict__ ws, int N, int bpb)
{
  const int b = blockIdx.y;
  const int t = threadIdx.x;
  const int lane = t & 63, w = t >> 6;
  const int c = lane & 15, g = lane >> 4;
  __shared__ int s_lab[4][256];
  __shared__ __align__(16) unsigned short s_embh[4][4 * EPAD];
  __shared__ float s_acc[160];                              // [label][5]
  for (int i = t; i < 160; i += 256) s_acc[i] = 0.f;
  __syncthreads();

  const size_t off = (size_t)b * N;
  const int*   instb = inst + off;
  const float* kernb = kern + off;
  const float* tmb   = tmask + off;
  const float* embb  = emb + (size_t)b * 4 * N;
  float* gout = ws + (size_t)b * 224;

  f32x4 acc0 = {0.f, 0.f, 0.f, 0.f};
  f32x4 acc1 = {0.f, 0.f, 0.f, 0.f};
  const int S = bpb * 4;               // wave stride in tiles
  const int wave_id = blockIdx.x * 4 + w;
  const int tiles = N >> 8;

#define P1_STAGE_COMPUTE(R, tnext)                                         \
  {                                                                        \
    int4 lb;                                                               \
    lb.x = (R.T.x > 0.5f && R.Kk.x > 0.5f) ? (R.L.x & 31) : 0;             \
    lb.y = (R.T.y > 0.5f && R.Kk.y > 0.5f) ? (R.L.y & 31) : 0;             \
    lb.z = (R.T.z > 0.5f && R.Kk.z > 0.5f) ? (R.L.z & 31) : 0;             \
    lb.w = (R.T.w > 0.5f && R.Kk.w > 0.5f) ? (R.L.w & 31) : 0;             \
    *(int4*)&s_lab[w][lane * 4] = lb;                                      \
    uint2 r;                                                               \
    r.x = pkrtz(R.E0.x, R.E0.y); r.y = pkrtz(R.E0.z, R.E0.w);              \
    *(uint2*)&s_embh[w][0 * EPAD + lane * 4] = r;                          \
    r.x = pkrtz(R.E1.x, R.E1.y); r.y = pkrtz(R.E1.z, R.E1.w);              \
    *(uint2*)&s_embh[w][1 * EPAD + lane * 4] = r;                          \
    r.x = pkrtz(R.E2.x, R.E2.y); r.y = pkrtz(R.E2.z, R.E2.w);              \
    *(uint2*)&s_embh[w][2 * EPAD + lane * 4] = r;                          \
    r.x = pkrtz(R.E3.x, R.E3.y); r.y = pkrtz(R.E3.z, R.E3.w);              \
    *(uint2*)&s_embh[w][3 * EPAD + lane * 4] = r;                          \
    if ((tnext) < tiles)                                                   \
      load_tile(R, instb, kernb, tmb, embb, N, ((tnext) << 8) + lane * 4); \
    _Pragma("unroll")                                                      \
    for (int j = 0; j < 8; ++j) {                                          \
      const int p8 = j * 32 + g * 8;                                       \
      const int4 l0 = *(const int4*)&s_lab[w][p8];                         \
      const int4 l1 = *(const int4*)&s_lab[w][p8 + 4];                     \
      hfrag fa0, fa1, fb;                                                  \
      fa0.u[0] = ohpair16(l0.x, l0.y, c);                                  \
      fa0.u[1] = ohpair16(l0.z, l0.w, c);                                  \
      fa0.u[2] = ohpair16(l1.x, l1.y, c);                                  \
      fa0.u[3] = ohpair16(l1.z, l1.w, c);                                  \
      fa1.u[0] = ohpair16(l0.x, l0.y, c + 16);                             \
      fa1.u[1] = ohpair16(l0.z, l0.w, c + 16);                             \
      fa1.u[2] = ohpair16(l1.x, l1.y, c + 16);                             \
      fa1.u[3] = ohpair16(l1.z, l1.w, c + 16);                             \
      if (c < 4) {                                                         \
        fb.v = *(const half8*)&s_embh[w][c * EPAD + p8];                   \
      } else if (c == 4) {                                                 \
        fb.u[0] = fb.u[1] = fb.u[2] = fb.u[3] = 0x3C003C00u;               \
      } else {                                                             \
        fb.u[0] = fb.u[1] = fb.u[2] = fb.u[3] = 0u;                        \
      }                                                                    \
      acc0 = __builtin_amdgcn_mfma_f32_16x16x32_f16(fa0.v, fb.v, acc0, 0, 0, 0); \
      acc1 = __builtin_amdgcn_mfma_f32_16x16x32_f16(fa1.v, fb.v, acc1, 0, 0, 0); \
    }                                                                      \
  }

  {
    Tile RA, RB, RC;
    int tile = wave_id;
    if (tile < tiles)
      load_tile(RA, instb, kernb, tmb, embb, N, (tile << 8) + lane * 4);
    if (tile + S < tiles)
      load_tile(RB, instb, kernb, tmb, embb, N, ((tile + S) << 8) + lane * 4);
    if (tile + 2 * S < tiles)
      load_tile(RC, instb, kernb, tmb, embb, N, ((tile + 2 * S) << 8) + lane * 4);
    while (tile < tiles) {
      P1_STAGE_COMPUTE(RA, tile + 3 * S)
      tile += S;
      if (tile >= tiles) break;
      P1_STAGE_COMPUTE(RB, tile + 3 * S)
      tile += S;
      if (tile >= tiles) break;
      P1_STAGE_COMPUTE(RC, tile + 3 * S)
      tile += S;
    }
  }
#undef P1_STAGE_COMPUTE

  if (c < 5) {
#pragma unroll
    for (int jj = 0; jj < 4; ++jj) {
      const int row = g * 4 + jj;
      atomicAdd(&s_acc[row * 5 + c], acc0[jj]);
      atomicAdd(&s_acc[(16 + row) * 5 + c], acc1[jj]);
    }
  }
  if ((N & 255) != 0 && blockIdx.x == 0) {    // generic tail (dead at 640x640)
    for (int i = ((N >> 8) << 8) + t; i < N; i += 256) {
      int lab = (tmb[i] > 0.5f && kernb[i] > 0.5f) ? (instb[i] & 31) : 0;
      atomicAdd(&gout[32 + lab], 1.f);
      atomicAdd(&gout[64 + lab],  embb[i]);
      atomicAdd(&gout[96 + lab],  embb[(size_t)N + i]);
      atomicAdd(&gout[128 + lab], embb[(size_t)2 * N + i]);
      atomicAdd(&gout[160 + lab], embb[(size_t)3 * N + i]);
    }
  }
  __syncthreads();
  if (t < 160) {
    float v = s_acc[t];
    if (v != 0.f) {
      const int row = t / 5, cc = t % 5;
      if (cc < 4) atomicAdd(&gout[64 + cc * 32 + row], v);
      else        atomicAdd(&gout[32 + row], v);
    }
  }
}

// ---------------- pass2: streaming MFMA one-hot over (val, 1) ---------------
// Reads originals (L3-hot after pass1); all loads cacheable.
__global__ __launch_bounds__(256)
void pass2_kernel(const float* __restrict__ emb, const int* __restrict__ inst,
                  const float* __restrict__ tmask, const float* __restrict__ maxd,
                  float* __restrict__ ws, int N, int B, int bpb)
{
  const int b = blockIdx.y;
  const int t = threadIdx.x;
  const int lane = t & 63, w = t >> 6;
  const int c = lane & 15, g = lane >> 4;
  __shared__ int s_lab[4][256];
  __shared__ __align__(16) unsigned short s_val[4][256];
  __shared__ __align__(16) float4 s_meanv[KI];
  __shared__ float s_scal[KI];
  __shared__ float s_acc[64];   // [0..31] valsum, [32..63] cnt
  float* gacc = ws + (size_t)b * 224;
  if (t < KI) {
    float inv = (t == 0) ? 0.f : 1.0f / fmaxf(gacc[32 + t], 1.0f);
    float4 m;
    m.x = gacc[64 + t]  * inv;
    m.y = gacc[96 + t]  * inv;
    m.z = gacc[128 + t] * inv;
    m.w = gacc[160 + t] * inv;
    s_meanv[t] = m;
    s_scal[t] = expf(maxd[b * KI + t]);
  }
  for (int i = t; i < 64; i += 256) s_acc[i] = 0.f;
  __syncthreads();

  const size_t off = (size_t)b * N;
  const int*   instb = inst + off;
  const float* tmb   = tmask + off;
  const float* embb  = emb + (size_t)b * 4 * N;

  f32x4 acc0 = {0.f, 0.f, 0.f, 0.f};
  f32x4 acc1 = {0.f, 0.f, 0.f, 0.f};
  const int waves_total = bpb * 4;
  const int wave_id = blockIdx.x * 4 + w;
  const int tiles = N >> 8;

  int tile = wave_id;
  i32x4 L; f32x4 T, E0, E1, E2, E3;
  if (tile < tiles) {
    const int p0 = (tile << 8) + lane * 4;
    L  = *(const i32x4*)(instb + p0);
    T  = *(const f32x4*)(tmb + p0);
    E0 = *(const f32x4*)(embb + p0);
    E1 = *(const f32x4*)(embb + (size_t)N + p0);
    E2 = *(const f32x4*)(embb + (size_t)2 * N + p0);
    E3 = *(const f32x4*)(embb + (size_t)3 * N + p0);
  }
  while (tile < tiles) {
    int4 lb;
    lb.x = (T.x > 0.5f) ? (L.x & 31) : 0;
    lb.y = (T.y > 0.5f) ? (L.y & 31) : 0;
    lb.z = (T.z > 0.5f) ? (L.z & 31) : 0;
    lb.w = (T.w > 0.5f) ? (L.w & 31) : 0;
    *(int4*)&s_lab[w][lane * 4] = lb;
    float v0, v1, v2, v3;
#define VALC(res, li, a0, a1, a2, a3) {                                  \
      float4 mn = s_meanv[li];                                           \
      float sc = s_scal[li];                                             \
      float d0 = (a0) - mn.x, d1 = (a1) - mn.y;                          \
      float d2 = (a2) - mn.z, d3 = (a3) - mn.w;                          \
      float dd = sqrtf(d0 * d0 + d1 * d1 + d2 * d2 + d3 * d3);           \
      float aa = fmaxf(sc * dd - 0.5f, 0.f);                             \
      res = __logf(aa * aa + 1.f); }
    VALC(v0, lb.x, E0.x, E1.x, E2.x, E3.x)
    VALC(v1, lb.y, E0.y, E1.y, E2.y, E3.y)
    VALC(v2, lb.z, E0.z, E1.z, E2.z, E3.z)
    VALC(v3, lb.w, E0.w, E1.w, E2.w, E3.w)
#undef VALC
    uint2 vr;
    vr.x = pkrtz(v0, v1); vr.y = pkrtz(v2, v3);
    *(uint2*)&s_val[w][lane * 4] = vr;

    const int next = tile + waves_total;
    if (next < tiles) {
      const int p0 = (next << 8) + lane * 4;
      L  = *(const i32x4*)(instb + p0);
      T  = *(const f32x4*)(tmb + p0);
      E0 = *(const f32x4*)(embb + p0);
      E1 = *(const f32x4*)(embb + (size_t)N + p0);
      E2 = *(const f32x4*)(embb + (size_t)2 * N + p0);
      E3 = *(const f32x4*)(embb + (size_t)3 * N + p0);
    }
#pragma unroll
    for (int j = 0; j < 8; ++j) {
      const int p8 = j * 32 + g * 8;
      const int4 l0 = *(const int4*)&s_lab[w][p8];
      const int4 l1 = *(const int4*)&s_lab[w][p8 + 4];
      hfrag fa0, fa1, fb;
      fa0.u[0] = ohpair16(l0.x, l0.y, c);
      fa0.u[1] = ohpair16(l0.z, l0.w, c);
      fa0.u[2] = ohpair16(l1.x, l1.y, c);
      fa0.u[3] = ohpair16(l1.z, l1.w, c);
      fa1.u[0] = ohpair16(l0.x, l0.y, c + 16);
      fa1.u[1] = ohpair16(l0.z, l0.w, c + 16);
      fa1.u[2] = ohpair16(l1.x, l1.y, c + 16);
      fa1.u[3] = ohpair16(l1.z, l1.w, c + 16);
      if (c == 0) {
        fb.v = *(const half8*)&s_val[w][p8];
      } else if (c == 1) {
        fb.u[0] = fb.u[1] = fb.u[2] = fb.u[3] = 0x3C003C00u;  // col1 = 1.0
      } else {
        fb.u[0] = fb.u[1] = fb.u[2] = fb.u[3] = 0u;
      }
      acc0 = __builtin_amdgcn_mfma_f32_16x16x32_f16(fa0.v, fb.v, acc0, 0, 0, 0);
      acc1 = __builtin_amdgcn_mfma_f32_16x16x32_f16(fa1.v, fb.v, acc1, 0, 0, 0);
    }
    tile = next;
  }

  if (c < 2) {
#pragma unroll
    for (int jj = 0; jj < 4; ++jj) {
      const int row = g * 4 + jj;
      atomicAdd(&s_acc[c * 32 + row], acc0[jj]);
      atomicAdd(&s_acc[c * 32 + 16 + row], acc1[jj]);
    }
  }
  if ((N & 255) != 0 && blockIdx.x == 0) {    // generic tail (dead here)
    for (int i = ((N >> 8) << 8) + t; i < N; i += 256) {
      int lab = (tmb[i] > 0.5f) ? (instb[i] & 31) : 0;
      float4 mn = s_meanv[lab];
      float sc = s_scal[lab];
      float d0 = embb[i] - mn.x;
      float d1 = embb[(size_t)N + i] - mn.y;
      float d2 = embb[(size_t)2 * N + i] - mn.z;
      float d3 = embb[(size_t)3 * N + i] - mn.w;
      float dd = sqrtf(d0 * d0 + d1 * d1 + d2 * d2 + d3 * d3);
      float aa = fmaxf(sc * dd - 0.5f, 0.f);
      atomicAdd(&gacc[192 + lab], __logf(aa * aa + 1.f));
      atomicAdd(&gacc[lab], 1.f);
    }
  }
  __syncthreads();
  if (t < 64) {
    float v = s_acc[t];
    if (v != 0.f) {
      if (t < 32) atomicAdd(&gacc[192 + t], v);   // valsum
      else        atomicAdd(&gacc[t - 32], v);    // cnt
    }
  }
}

// ------------- bg_kernel: means + pairwise + l_reg + bg term ---------------
__global__ __launch_bounds__(256)
void bg_kernel(const float* __restrict__ emb, const int* __restrict__ inst,
               const float* __restrict__ tmask, float* __restrict__ ws, int N, int B)
{
  const int b = blockIdx.x;
  const int t = threadIdx.x;
  const int lane = t & 63, wave = t >> 6;
  float* gacc = ws + (size_t)b * 224;
  __shared__ float mean[KI][4];
  __shared__ int s_bgidx[BG_SAMPLE];
  __shared__ int s_count;
  __shared__ int s_wcnt[4];
  if (t == 0) s_count = 0;
  if (t < KI) {
    float inv = (t == 0) ? 0.f : 1.0f / fmaxf(gacc[32 + t], 1.0f);
    mean[t][0] = gacc[64 + t]  * inv;
    mean[t][1] = gacc[96 + t]  * inv;
    mean[t][2] = gacc[128 + t] * inv;
    mean[t][3] = gacc[160 + t] * inv;
  }
  __syncthreads();
  const int*   instb = inst + (size_t)b * N;
  const float* tmb   = tmask + (size_t)b * N;

  for (int base = 0; base < N; base += 256) {
    if (s_count >= BG_SAMPLE) break;
    int i = base + t;
    bool p = false;
    if (i < N) {
      int lab = instb[i];
      if (tmb[i] <= 0.5f) lab = 0;
      p = (lab == 0);
    }
    unsigned long long m = __ballot(p);
    if (lane == 0) s_wcnt[wave] = __popcll(m);
    __syncthreads();
    int pos = s_count;
    for (int ww = 0; ww < wave; ++ww) pos += s_wcnt[ww];
    if (p) {
      pos += __popcll(m & ((1ull << lane) - 1ull));
      if (pos < BG_SAMPLE) s_bgidx[pos] = i;
    }
    __syncthreads();
    if (t == 0) s_count += s_wcnt[0] + s_wcnt[1] + s_wcnt[2] + s_wcnt[3];
    __syncthreads();
  }
  if (s_count < BG_SAMPLE) {   // stable-argsort fallback: first non-bg indices
    for (int base = 0; base < N; base += 256) {
      if (s_count >= BG_SAMPLE) break;
      int i = base + t;
      bool p = false;
      if (i < N) {
        int lab = instb[i];
        if (tmb[i] <= 0.5f) lab = 0;
        p = (lab != 0);
      }
      unsigned long long m = __ballot(p);
      if (lane == 0) s_wcnt[wave] = __popcll(m);
      __syncthreads();
      int pos = s_count;
      for (int ww = 0; ww < wave; ++ww) pos += s_wcnt[ww];
      if (p) {
        pos += __popcll(m & ((1ull << lane) - 1ull));
        if (pos < BG_SAMPLE) s_bgidx[pos] = i;
      }
      __syncthreads();
      if (t == 0) s_count += s_wcnt[0] + s_wcnt[1] + s_wcnt[2] + s_wcnt[3];
      __syncthreads();
    }
  }
  __syncthreads();

  __shared__ float ebg[BG_SAMPLE][4];
  const float* embb = emb + (size_t)b * 4 * N;
  for (int j = t; j < BG_SAMPLE; j += 256) {
    int i = s_bgidx[j];
    ebg[j][0] = embb[i];
    ebg[j][1] = embb[(size_t)N + i];
    ebg[j][2] = embb[(size_t)2 * N + i];
    ebg[j][3] = embb[(size_t)3 * N + i];
  }
  __syncthreads();

  const float coef = 1.0f - expf(-10.0f / 32.0f);
  float lp = 0.f;
  for (int idx = t; idx < 31 * 31; idx += 256) {
    int i = 1 + idx / 31, j = 1 + idx % 31;
    if (i == j) continue;
    float d0 = mean[i][0] - mean[j][0];
    float d1 = mean[i][1] - mean[j][1];
    float d2 = mean[i][2] - mean[j][2];
    float d3 = mean[i][3] - mean[j][3];
    float pd = sqrtf(d0 * d0 + d1 * d1 + d2 * d2 + d3 * d3);
    float a = fmaxf(3.0f - coef * pd, 0.f);
    lp += logf(a * a + 1.f);
  }
  float lr = 0.f;
  for (int k = t; k < KI; k += 256) {
    float n = sqrtf(mean[k][0] * mean[k][0] + mean[k][1] * mean[k][1] +
                    mean[k][2] * mean[k][2] + mean[k][3] * mean[k][3]);
    lr += logf(n + 1.f);
  }
  float lbg = 0.f;
  for (int idx = t; idx < 31 * BG_SAMPLE; idx += 256) {
    int k = 1 + idx / BG_SAMPLE, j = idx % BG_SAMPLE;
    float d0 = ebg[j][0] - mean[k][0];
    float d1 = ebg[j][1] - mean[k][1];
    float d2 = ebg[j][2] - mean[k][2];
    float d3 = ebg[j][3] - mean[k][3];
    float dd = sqrtf(d0 * d0 + d1 * d1 + d2 * d2 + d3 * d3);
    float a = fmaxf(3.0f - coef * dd, 0.f);
    lbg += logf(a * a + 1.f);
  }
  float a0 = waveReduceSum(lp);
  float a1 = waveReduceSum(lr);
  float a2 = waveReduceSum(lbg);
  __shared__ float red[3][4];
  if (lane == 0) { red[0][wave] = a0; red[1][wave] = a1; red[2][wave] = a2; }
  __syncthreads();
  if (t == 0) {
    float* gmisc = ws + (size_t)B * 224 + (size_t)B * 128 + (size_t)b * 4;
    gmisc[0] = red[0][0] + red[0][1] + red[0][2] + red[0][3];
    gmisc[1] = (red[1][0] + red[1][1] + red[1][2] + red[1][3]) * (0.001f / 32.0f);
    gmisc[2] = (red[2][0] + red[2][1] + red[2][2] + red[2][3]) * (1.0f / BG_SAMPLE);
  }
}

__global__ __launch_bounds__(64)
void final_kernel(const float* __restrict__ ws, float* __restrict__ out, int B)
{
  const int t = threadIdx.x;
  __shared__ float s[64];
  float tot = 0.f;
  if (t < B) {
    const float* gacc  = ws + (size_t)t * 224;
    const float* gmisc = ws + (size_t)B * 224 + (size_t)B * 128 + (size_t)t * 4;
    float lagg = 0.f;
    for (int k = 1; k < KI; ++k)
      lagg += gacc[192 + k] / fmaxf(gacc[k], 1.0f);
    lagg *= (1.0f / 31.0f);
    float ldis = (gmisc[0] + gmisc[2]) * (1.0f / 961.0f);  // (K-1)(K-2)+(K-1)
    tot = lagg + ldis + gmisc[1];
  }
  s[t] = tot;
  __syncthreads();
  if (t == 0) {
    float sum = 0.f;
    for (int b = 0; b < B; ++b) sum += s[b];
    out[0] = sum / (float)B;
  }
}

extern "C" void kernel_launch(void* const* d_in, const int* in_sizes, int n_in,
                              void* d_out, int out_size, void* d_ws, size_t ws_size,
                              hipStream_t stream)
{
  const float* emb   = (const float*)d_in[0];
  const int*   inst  = (const int*)d_in[1];
  const float* kern  = (const float*)d_in[2];
  const float* tmask = (const float*)d_in[3];
  const float* maxd  = (const float*)d_in[5];
  float* out = (float*)d_out;
  float* ws  = (float*)d_ws;

  const int B = in_sizes[5] / KI;          // 16
  const int N = in_sizes[1] / B;           // 409600
  const int bpb1 = 100;                    // pass1: 400 waves/batch, 4 tiles each
  const int bpb2 = 100;                    // pass2: L3-hot

  if (ws_size < (size_t)B * 356 * sizeof(float)) return;

  hipMemsetAsync(d_ws, 0, (size_t)B * 356 * sizeof(float), stream);
  pass1_kernel<<<dim3(bpb1, B), 256, 0, stream>>>(emb, inst, kern, tmask, ws, N, bpb1);
  pass2_kernel<<<dim3(bpb2, B), 256, 0, stream>>>(emb, inst, tmask, maxd, ws, N, B, bpb2);
  bg_kernel<<<B, 256, 0, stream>>>(emb, inst, tmask, ws, N, B);
  final_kernel<<<1, 64, 0, stream>>>(ws, out, B);
}

// Round 12
// 93.936 us; speedup vs baseline: 1.1379x; 1.1379x over previous
//
#include <hip/hip_runtime.h>

#define KI 32
#define BG_SAMPLE 100
#define EPAD 272   // s_embh row stride in halves (256 + 16 pad)

// ws float layout (per batch b at b*224):
//   acc[224] = { cnt[32], cntk[32], sums d-major [4][32], valsum[32] }
// misc[B][4] = {sum_pair,l_reg,sum_bg,pad} at B*224+B*128 + b*4.
// total B*356 floats.

typedef __attribute__((ext_vector_type(8))) _Float16 half8;
typedef __attribute__((ext_vector_type(4))) float f32x4;
typedef __attribute__((ext_vector_type(4))) int i32x4;
typedef union { unsigned u[4]; half8 v; } hfrag;

static __device__ __forceinline__ unsigned pkrtz(float a, float b) {
  unsigned d;
  asm("v_cvt_pkrtz_f16_f32 %0, %1, %2" : "=v"(d) : "v"(a), "v"(b));
  return d;
}
static __device__ __forceinline__ unsigned ohpair16(int la, int lb_, int r) {
  return ((la == r) ? 0x3C00u : 0u) | ((lb_ == r) ? 0x3C000000u : 0u);
}
static __device__ __forceinline__ float waveReduceSum(float v) {
#pragma unroll
  for (int off = 32; off > 0; off >>= 1) v += __shfl_down(v, off, 64);
  return v;
}

// ---------------- pass1: full-NT streaming MFMA one-hot --------------------
__global__ __launch_bounds__(256)
void pass1_kernel(const float* __restrict__ emb, const int* __restrict__ inst,
                  const float* __restrict__ kern, const float* __restrict__ tmask,
                  float* __restrict__ ws, int N, int bpb)
{
  const int b = blockIdx.y;
  const int t = threadIdx.x;
  const int lane = t & 63, w = t >> 6;
  const int c = lane & 15, g = lane >> 4;
  __shared__ int s_lab[4][256];
  __shared__ __align__(16) unsigned short s_embh[4][4 * EPAD];
  __shared__ float s_acc[160];                              // [label][5]
  for (int i = t; i < 160; i += 256) s_acc[i] = 0.f;
  __syncthreads();

  const size_t off = (size_t)b * N;
  const int*   instb = inst + off;
  const float* kernb = kern + off;
  const float* tmb   = tmask + off;
  const float* embb  = emb + (size_t)b * 4 * N;
  float* gout = ws + (size_t)b * 224;

  f32x4 acc0 = {0.f, 0.f, 0.f, 0.f};
  f32x4 acc1 = {0.f, 0.f, 0.f, 0.f};
  const int waves_total = bpb * 4;
  const int wave_id = blockIdx.x * 4 + w;
  const int tiles = N >> 8;

  int tile = wave_id;
  i32x4 L; f32x4 T, Kk, E0, E1, E2, E3;
  if (tile < tiles) {
    const int p0 = (tile << 8) + lane * 4;
    L  = __builtin_nontemporal_load((const i32x4*)(instb + p0));
    T  = __builtin_nontemporal_load((const f32x4*)(tmb + p0));
    Kk = __builtin_nontemporal_load((const f32x4*)(kernb + p0));
    E0 = __builtin_nontemporal_load((const f32x4*)(embb + p0));
    E1 = __builtin_nontemporal_load((const f32x4*)(embb + (size_t)N + p0));
    E2 = __builtin_nontemporal_load((const f32x4*)(embb + (size_t)2 * N + p0));
    E3 = __builtin_nontemporal_load((const f32x4*)(embb + (size_t)3 * N + p0));
  }
  while (tile < tiles) {
    int4 lb;
    lb.x = (T.x > 0.5f && Kk.x > 0.5f) ? (L.x & 31) : 0;
    lb.y = (T.y > 0.5f && Kk.y > 0.5f) ? (L.y & 31) : 0;
    lb.z = (T.z > 0.5f && Kk.z > 0.5f) ? (L.z & 31) : 0;
    lb.w = (T.w > 0.5f && Kk.w > 0.5f) ? (L.w & 31) : 0;
    *(int4*)&s_lab[w][lane * 4] = lb;
    uint2 r;
    r.x = pkrtz(E0.x, E0.y); r.y = pkrtz(E0.z, E0.w);
    *(uint2*)&s_embh[w][0 * EPAD + lane * 4] = r;
    r.x = pkrtz(E1.x, E1.y); r.y = pkrtz(E1.z, E1.w);
    *(uint2*)&s_embh[w][1 * EPAD + lane * 4] = r;
    r.x = pkrtz(E2.x, E2.y); r.y = pkrtz(E2.z, E2.w);
    *(uint2*)&s_embh[w][2 * EPAD + lane * 4] = r;
    r.x = pkrtz(E3.x, E3.y); r.y = pkrtz(E3.z, E3.w);
    *(uint2*)&s_embh[w][3 * EPAD + lane * 4] = r;

    const int next = tile + waves_total;
    if (next < tiles) {                      // prefetch next tile into regs
      const int p0 = (next << 8) + lane * 4;
      L  = __builtin_nontemporal_load((const i32x4*)(instb + p0));
      T  = __builtin_nontemporal_load((const f32x4*)(tmb + p0));
      Kk = __builtin_nontemporal_load((const f32x4*)(kernb + p0));
      E0 = __builtin_nontemporal_load((const f32x4*)(embb + p0));
      E1 = __builtin_nontemporal_load((const f32x4*)(embb + (size_t)N + p0));
      E2 = __builtin_nontemporal_load((const f32x4*)(embb + (size_t)2 * N + p0));
      E3 = __builtin_nontemporal_load((const f32x4*)(embb + (size_t)3 * N + p0));
    }
#pragma unroll
    for (int j = 0; j < 8; ++j) {
      const int p8 = j * 32 + g * 8;
      const int4 l0 = *(const int4*)&s_lab[w][p8];
      const int4 l1 = *(const int4*)&s_lab[w][p8 + 4];
      hfrag fa0, fa1, fb;
      fa0.u[0] = ohpair16(l0.x, l0.y, c);
      fa0.u[1] = ohpair16(l0.z, l0.w, c);
      fa0.u[2] = ohpair16(l1.x, l1.y, c);
      fa0.u[3] = ohpair16(l1.z, l1.w, c);
      fa1.u[0] = ohpair16(l0.x, l0.y, c + 16);
      fa1.u[1] = ohpair16(l0.z, l0.w, c + 16);
      fa1.u[2] = ohpair16(l1.x, l1.y, c + 16);
      fa1.u[3] = ohpair16(l1.z, l1.w, c + 16);
      if (c < 4) {
        fb.v = *(const half8*)&s_embh[w][c * EPAD + p8];
      } else if (c == 4) {
        fb.u[0] = fb.u[1] = fb.u[2] = fb.u[3] = 0x3C003C00u;  // col4 = 1.0
      } else {
        fb.u[0] = fb.u[1] = fb.u[2] = fb.u[3] = 0u;
      }
      acc0 = __builtin_amdgcn_mfma_f32_16x16x32_f16(fa0.v, fb.v, acc0, 0, 0, 0);
      acc1 = __builtin_amdgcn_mfma_f32_16x16x32_f16(fa1.v, fb.v, acc1, 0, 0, 0);
    }
    tile = next;
  }

  if (c < 5) {
#pragma unroll
    for (int jj = 0; jj < 4; ++jj) {
      const int row = g * 4 + jj;
      atomicAdd(&s_acc[row * 5 + c], acc0[jj]);
      atomicAdd(&s_acc[(16 + row) * 5 + c], acc1[jj]);
    }
  }
  if ((N & 255) != 0 && blockIdx.x == 0) {    // generic tail (dead at 640x640)
    for (int i = ((N >> 8) << 8) + t; i < N; i += 256) {
      int lab = (tmb[i] > 0.5f && kernb[i] > 0.5f) ? (instb[i] & 31) : 0;
      atomicAdd(&gout[32 + lab], 1.f);
      atomicAdd(&gout[64 + lab],  embb[i]);
      atomicAdd(&gout[96 + lab],  embb[(size_t)N + i]);
      atomicAdd(&gout[128 + lab], embb[(size_t)2 * N + i]);
      atomicAdd(&gout[160 + lab], embb[(size_t)3 * N + i]);
    }
  }
  __syncthreads();
  if (t < 160) {
    float v = s_acc[t];
    if (v != 0.f) {
      const int row = t / 5, cc = t % 5;
      if (cc < 4) atomicAdd(&gout[64 + cc * 32 + row], v);
      else        atomicAdd(&gout[32 + row], v);
    }
  }
}

// ---------------- pass2: full-NT streaming MFMA one-hot over (val, 1) ------
__global__ __launch_bounds__(256)
void pass2_kernel(const float* __restrict__ emb, const int* __restrict__ inst,
                  const float* __restrict__ tmask, const float* __restrict__ maxd,
                  float* __restrict__ ws, int N, int B, int bpb)
{
  const int b = blockIdx.y;
  const int t = threadIdx.x;
  const int lane = t & 63, w = t >> 6;
  const int c = lane & 15, g = lane >> 4;
  __shared__ int s_lab[4][256];
  __shared__ __align__(16) unsigned short s_val[4][256];
  __shared__ __align__(16) float4 s_meanv[KI];
  __shared__ float s_scal[KI];
  __shared__ float s_acc[64];   // [0..31] valsum, [32..63] cnt
  float* gacc = ws + (size_t)b * 224;
  if (t < KI) {
    float inv = (t == 0) ? 0.f : 1.0f / fmaxf(gacc[32 + t], 1.0f);
    float4 m;
    m.x = gacc[64 + t]  * inv;
    m.y = gacc[96 + t]  * inv;
    m.z = gacc[128 + t] * inv;
    m.w = gacc[160 + t] * inv;
    s_meanv[t] = m;
    s_scal[t] = expf(maxd[b * KI + t]);
  }
  for (int i = t; i < 64; i += 256) s_acc[i] = 0.f;
  __syncthreads();

  const size_t off = (size_t)b * N;
  const int*   instb = inst + off;
  const float* tmb   = tmask + off;
  const float* embb  = emb + (size_t)b * 4 * N;

  f32x4 acc0 = {0.f, 0.f, 0.f, 0.f};
  f32x4 acc1 = {0.f, 0.f, 0.f, 0.f};
  const int waves_total = bpb * 4;
  const int wave_id = blockIdx.x * 4 + w;
  const int tiles = N >> 8;

  int tile = wave_id;
  i32x4 L; f32x4 T, E0, E1, E2, E3;
  if (tile < tiles) {
    const int p0 = (tile << 8) + lane * 4;
    L  = __builtin_nontemporal_load((const i32x4*)(instb + p0));
    T  = __builtin_nontemporal_load((const f32x4*)(tmb + p0));
    E0 = __builtin_nontemporal_load((const f32x4*)(embb + p0));
    E1 = __builtin_nontemporal_load((const f32x4*)(embb + (size_t)N + p0));
    E2 = __builtin_nontemporal_load((const f32x4*)(embb + (size_t)2 * N + p0));
    E3 = __builtin_nontemporal_load((const f32x4*)(embb + (size_t)3 * N + p0));
  }
  while (tile < tiles) {
    int4 lb;
    lb.x = (T.x > 0.5f) ? (L.x & 31) : 0;
    lb.y = (T.y > 0.5f) ? (L.y & 31) : 0;
    lb.z = (T.z > 0.5f) ? (L.z & 31) : 0;
    lb.w = (T.w > 0.5f) ? (L.w & 31) : 0;
    *(int4*)&s_lab[w][lane * 4] = lb;
    float v0, v1, v2, v3;
#define VALC(res, li, a0, a1, a2, a3) {                                  \
      float4 mn = s_meanv[li];                                           \
      float sc = s_scal[li];                                             \
      float d0 = (a0) - mn.x, d1 = (a1) - mn.y;                          \
      float d2 = (a2) - mn.z, d3 = (a3) - mn.w;                          \
      float dd = sqrtf(d0 * d0 + d1 * d1 + d2 * d2 + d3 * d3);           \
      float aa = fmaxf(sc * dd - 0.5f, 0.f);                             \
      res = __logf(aa * aa + 1.f); }
    VALC(v0, lb.x, E0.x, E1.x, E2.x, E3.x)
    VALC(v1, lb.y, E0.y, E1.y, E2.y, E3.y)
    VALC(v2, lb.z, E0.z, E1.z, E2.z, E3.z)
    VALC(v3, lb.w, E0.w, E1.w, E2.w, E3.w)
#undef VALC
    uint2 vr;
    vr.x = pkrtz(v0, v1); vr.y = pkrtz(v2, v3);
    *(uint2*)&s_val[w][lane * 4] = vr;

    const int next = tile + waves_total;
    if (next < tiles) {
      const int p0 = (next << 8) + lane * 4;
      L  = __builtin_nontemporal_load((const i32x4*)(instb + p0));
      T  = __builtin_nontemporal_load((const f32x4*)(tmb + p0));
      E0 = __builtin_nontemporal_load((const f32x4*)(embb + p0));
      E1 = __builtin_nontemporal_load((const f32x4*)(embb + (size_t)N + p0));
      E2 = __builtin_nontemporal_load((const f32x4*)(embb + (size_t)2 * N + p0));
      E3 = __builtin_nontemporal_load((const f32x4*)(embb + (size_t)3 * N + p0));
    }
#pragma unroll
    for (int j = 0; j < 8; ++j) {
      const int p8 = j * 32 + g * 8;
      const int4 l0 = *(const int4*)&s_lab[w][p8];
      const int4 l1 = *(const int4*)&s_lab[w][p8 + 4];
      hfrag fa0, fa1, fb;
      fa0.u[0] = ohpair16(l0.x, l0.y, c);
      fa0.u[1] = ohpair16(l0.z, l0.w, c);
      fa0.u[2] = ohpair16(l1.x, l1.y, c);
      fa0.u[3] = ohpair16(l1.z, l1.w, c);
      fa1.u[0] = ohpair16(l0.x, l0.y, c + 16);
      fa1.u[1] = ohpair16(l0.z, l0.w, c + 16);
      fa1.u[2] = ohpair16(l1.x, l1.y, c + 16);
      fa1.u[3] = ohpair16(l1.z, l1.w, c + 16);
      if (c == 0) {
        fb.v = *(const half8*)&s_val[w][p8];
      } else if (c == 1) {
        fb.u[0] = fb.u[1] = fb.u[2] = fb.u[3] = 0x3C003C00u;  // col1 = 1.0
      } else {
        fb.u[0] = fb.u[1] = fb.u[2] = fb.u[3] = 0u;
      }
      acc0 = __builtin_amdgcn_mfma_f32_16x16x32_f16(fa0.v, fb.v, acc0, 0, 0, 0);
      acc1 = __builtin_amdgcn_mfma_f32_16x16x32_f16(fa1.v, fb.v, acc1, 0, 0, 0);
    }
    tile = next;
  }

  if (c < 2) {
#pragma unroll
    for (int jj = 0; jj < 4; ++jj) {
      const int row = g * 4 + jj;
      atomicAdd(&s_acc[c * 32 + row], acc0[jj]);
      atomicAdd(&s_acc[c * 32 + 16 + row], acc1[jj]);
    }
  }
  if ((N & 255) != 0 && blockIdx.x == 0) {    // generic tail (dead here)
    for (int i = ((N >> 8) << 8) + t; i < N; i += 256) {
      int lab = (tmb[i] > 0.5f) ? (instb[i] & 31) : 0;
      float4 mn = s_meanv[lab];
      float sc = s_scal[lab];
      float d0 = embb[i] - mn.x;
      float d1 = embb[(size_t)N + i] - mn.y;
      float d2 = embb[(size_t)2 * N + i] - mn.z;
      float d3 = embb[(size_t)3 * N + i] - mn.w;
      float dd = sqrtf(d0 * d0 + d1 * d1 + d2 * d2 + d3 * d3);
      float aa = fmaxf(sc * dd - 0.5f, 0.f);
      atomicAdd(&gacc[192 + lab], __logf(aa * aa + 1.f));
      atomicAdd(&gacc[lab], 1.f);
    }
  }
  __syncthreads();
  if (t < 64) {
    float v = s_acc[t];
    if (v != 0.f) {
      if (t < 32) atomicAdd(&gacc[192 + t], v);   // valsum
      else        atomicAdd(&gacc[t - 32], v);    // cnt
    }
  }
}

// ------------- bg_kernel: means + pairwise + l_reg + bg term ---------------
__global__ __launch_bounds__(256)
void bg_kernel(const float* __restrict__ emb, const int* __restrict__ inst,
               const float* __restrict__ tmask, float* __restrict__ ws, int N, int B)
{
  const int b = blockIdx.x;
  const int t = threadIdx.x;
  const int lane = t & 63, wave = t >> 6;
  float* gacc = ws + (size_t)b * 224;
  __shared__ float mean[KI][4];
  __shared__ int s_bgidx[BG_SAMPLE];
  __shared__ int s_count;
  __shared__ int s_wcnt[4];
  if (t == 0) s_count = 0;
  if (t < KI) {
    float inv = (t == 0) ? 0.f : 1.0f / fmaxf(gacc[32 + t], 1.0f);
    mean[t][0] = gacc[64 + t]  * inv;
    mean[t][1] = gacc[96 + t]  * inv;
    mean[t][2] = gacc[128 + t] * inv;
    mean[t][3] = gacc[160 + t] * inv;
  }
  __syncthreads();
  const int*   instb = inst + (size_t)b * N;
  const float* tmb   = tmask + (size_t)b * N;

  for (int base = 0; base < N; base += 256) {
    if (s_count >= BG_SAMPLE) break;
    int i = base + t;
    bool p = false;
    if (i < N) {
      int lab = instb[i];
      if (tmb[i] <= 0.5f) lab = 0;
      p = (lab == 0);
    }
    unsigned long long m = __ballot(p);
    if (lane == 0) s_wcnt[wave] = __popcll(m);
    __syncthreads();
    int pos = s_count;
    for (int ww = 0; ww < wave; ++ww) pos += s_wcnt[ww];
    if (p) {
      pos += __popcll(m & ((1ull << lane) - 1ull));
      if (pos < BG_SAMPLE) s_bgidx[pos] = i;
    }
    __syncthreads();
    if (t == 0) s_count += s_wcnt[0] + s_wcnt[1] + s_wcnt[2] + s_wcnt[3];
    __syncthreads();
  }
  if (s_count < BG_SAMPLE) {   // stable-argsort fallback: first non-bg indices
    for (int base = 0; base < N; base += 256) {
      if (s_count >= BG_SAMPLE) break;
      int i = base + t;
      bool p = false;
      if (i < N) {
        int lab = instb[i];
        if (tmb[i] <= 0.5f) lab = 0;
        p = (lab != 0);
      }
      unsigned long long m = __ballot(p);
      if (lane == 0) s_wcnt[wave] = __popcll(m);
      __syncthreads();
      int pos = s_count;
      for (int ww = 0; ww < wave; ++ww) pos += s_wcnt[ww];
      if (p) {
        pos += __popcll(m & ((1ull << lane) - 1ull));
        if (pos < BG_SAMPLE) s_bgidx[pos] = i;
      }
      __syncthreads();
      if (t == 0) s_count += s_wcnt[0] + s_wcnt[1] + s_wcnt[2] + s_wcnt[3];
      __syncthreads();
    }
  }
  __syncthreads();

  __shared__ float ebg[BG_SAMPLE][4];
  const float* embb = emb + (size_t)b * 4 * N;
  for (int j = t; j < BG_SAMPLE; j += 256) {
    int i = s_bgidx[j];
    ebg[j][0] = embb[i];
    ebg[j][1] = embb[(size_t)N + i];
    ebg[j][2] = embb[(size_t)2 * N + i];
    ebg[j][3] = embb[(size_t)3 * N + i];
  }
  __syncthreads();

  const float coef = 1.0f - expf(-10.0f / 32.0f);
  float lp = 0.f;
  for (int idx = t; idx < 31 * 31; idx += 256) {
    int i = 1 + idx / 31, j = 1 + idx % 31;
    if (i == j) continue;
    float d0 = mean[i][0] - mean[j][0];
    float d1 = mean[i][1] - mean[j][1];
    float d2 = mean[i][2] - mean[j][2];
    float d3 = mean[i][3] - mean[j][3];
    float pd = sqrtf(d0 * d0 + d1 * d1 + d2 * d2 + d3 * d3);
    float a = fmaxf(3.0f - coef * pd, 0.f);
    lp += logf(a * a + 1.f);
  }
  float lr = 0.f;
  for (int k = t; k < KI; k += 256) {
    float n = sqrtf(mean[k][0] * mean[k][0] + mean[k][1] * mean[k][1] +
                    mean[k][2] * mean[k][2] + mean[k][3] * mean[k][3]);
    lr += logf(n + 1.f);
  }
  float lbg = 0.f;
  for (int idx = t; idx < 31 * BG_SAMPLE; idx += 256) {
    int k = 1 + idx / BG_SAMPLE, j = idx % BG_SAMPLE;
    float d0 = ebg[j][0] - mean[k][0];
    float d1 = ebg[j][1] - mean[k][1];
    float d2 = ebg[j][2] - mean[k][2];
    float d3 = ebg[j][3] - mean[k][3];
    float dd = sqrtf(d0 * d0 + d1 * d1 + d2 * d2 + d3 * d3);
    float a = fmaxf(3.0f - coef * dd, 0.f);
    lbg += logf(a * a + 1.f);
  }
  float a0 = waveReduceSum(lp);
  float a1 = waveReduceSum(lr);
  float a2 = waveReduceSum(lbg);
  __shared__ float red[3][4];
  if (lane == 0) { red[0][wave] = a0; red[1][wave] = a1; red[2][wave] = a2; }
  __syncthreads();
  if (t == 0) {
    float* gmisc = ws + (size_t)B * 224 + (size_t)B * 128 + (size_t)b * 4;
    gmisc[0] = red[0][0] + red[0][1] + red[0][2] + red[0][3];
    gmisc[1] = (red[1][0] + red[1][1] + red[1][2] + red[1][3]) * (0.001f / 32.0f);
    gmisc[2] = (red[2][0] + red[2][1] + red[2][2] + red[2][3]) * (1.0f / BG_SAMPLE);
  }
}

__global__ __launch_bounds__(64)
void final_kernel(const float* __restrict__ ws, float* __restrict__ out, int B)
{
  const int t = threadIdx.x;
  __shared__ float s[64];
  float tot = 0.f;
  if (t < B) {
    const float* gacc  = ws + (size_t)t * 224;
    const float* gmisc = ws + (size_t)B * 224 + (size_t)B * 128 + (size_t)t * 4;
    float lagg = 0.f;
    for (int k = 1; k < KI; ++k)
      lagg += gacc[192 + k] / fmaxf(gacc[k], 1.0f);
    lagg *= (1.0f / 31.0f);
    float ldis = (gmisc[0] + gmisc[2]) * (1.0f / 961.0f);  // (K-1)(K-2)+(K-1)
    tot = lagg + ldis + gmisc[1];
  }
  s[t] = tot;
  __syncthreads();
  if (t == 0) {
    float sum = 0.f;
    for (int b = 0; b < B; ++b) sum += s[b];
    out[0] = sum / (float)B;
  }
}

extern "C" void kernel_launch(void* const* d_in, const int* in_sizes, int n_in,
                              void* d_out, int out_size, void* d_ws, size_t ws_size,
                              hipStream_t stream)
{
  const float* emb   = (const float*)d_in[0];
  const int*   inst  = (const int*)d_in[1];
  const float* kern  = (const float*)d_in[2];
  const float* tmask = (const float*)d_in[3];
  const float* maxd  = (const float*)d_in[5];
  float* out = (float*)d_out;
  float* ws  = (float*)d_ws;

  const int B = in_sizes[5] / KI;          // 16
  const int N = in_sizes[1] / B;           // 409600
  const int bpb = 100;                     // 400 waves/batch, 4 tiles each

  if (ws_size < (size_t)B * 356 * sizeof(float)) return;

  hipMemsetAsync(d_ws, 0, (size_t)B * 356 * sizeof(float), stream);
  pass1_kernel<<<dim3(bpb, B), 256, 0, stream>>>(emb, inst, kern, tmask, ws, N, bpb);
  pass2_kernel<<<dim3(bpb, B), 256, 0, stream>>>(emb, inst, tmask, maxd, ws, N, B, bpb);
  bg_kernel<<<B, 256, 0, stream>>>(emb, inst, tmask, ws, N, B);
  final_kernel<<<1, 64, 0, stream>>>(ws, out, B);
}

// Round 13
// 92.052 us; speedup vs baseline: 1.1612x; 1.0205x over previous
//
#include <hip/hip_runtime.h>

#define KI 32
#define BG_SAMPLE 100
#define EPAD 272   // s_embh row stride in halves (256 + 16 pad)

// ws float layout (per batch b at b*224):
//   acc[224] = { cnt[32], cntk[32], sums d-major [4][32], valsum[32] }
// misc[B][4] = {sum_pair,l_reg,sum_bg,pad} at B*224+B*128 + b*4.
// then lab8: u8 [B][N] (tm-composed labels), 4B-aligned after B*356 floats.

typedef __attribute__((ext_vector_type(8))) _Float16 half8;
typedef __attribute__((ext_vector_type(4))) float f32x4;
typedef __attribute__((ext_vector_type(4))) int i32x4;
typedef union { unsigned u[4]; half8 v; } hfrag;

static __device__ __forceinline__ unsigned pkrtz(float a, float b) {
  unsigned d;
  asm("v_cvt_pkrtz_f16_f32 %0, %1, %2" : "=v"(d) : "v"(a), "v"(b));
  return d;
}
static __device__ __forceinline__ unsigned ohpair16(int la, int lb_, int r) {
  return ((la == r) ? 0x3C00u : 0u) | ((lb_ == r) ? 0x3C000000u : 0u);
}
static __device__ __forceinline__ float waveReduceSum(float v) {
#pragma unroll
  for (int off = 32; off > 0; off >>= 1) v += __shfl_down(v, off, 64);
  return v;
}

// ------- pass1: full-NT streaming MFMA one-hot + lab8 mirror ---------------
__global__ __launch_bounds__(256)
void pass1_kernel(const float* __restrict__ emb, const int* __restrict__ inst,
                  const float* __restrict__ kern, const float* __restrict__ tmask,
                  float* __restrict__ ws, unsigned* __restrict__ lab8w,
                  int N, int bpb)
{
  const int b = blockIdx.y;
  const int t = threadIdx.x;
  const int lane = t & 63, w = t >> 6;
  const int c = lane & 15, g = lane >> 4;
  __shared__ int s_lab[4][256];
  __shared__ __align__(16) unsigned short s_embh[4][4 * EPAD];
  __shared__ float s_acc[160];                              // [label][5]
  for (int i = t; i < 160; i += 256) s_acc[i] = 0.f;
  __syncthreads();

  const size_t off = (size_t)b * N;
  const int*   instb = inst + off;
  const float* kernb = kern + off;
  const float* tmb   = tmask + off;
  const float* embb  = emb + (size_t)b * 4 * N;
  unsigned* labg = lab8w + (off >> 2);
  float* gout = ws + (size_t)b * 224;

  f32x4 acc0 = {0.f, 0.f, 0.f, 0.f};
  f32x4 acc1 = {0.f, 0.f, 0.f, 0.f};
  const int waves_total = bpb * 4;
  const int wave_id = blockIdx.x * 4 + w;
  const int tiles = N >> 8;

  int tile = wave_id;
  i32x4 L; f32x4 T, Kk, E0, E1, E2, E3;
  if (tile < tiles) {
    const int p0 = (tile << 8) + lane * 4;
    L  = __builtin_nontemporal_load((const i32x4*)(instb + p0));
    T  = __builtin_nontemporal_load((const f32x4*)(tmb + p0));
    Kk = __builtin_nontemporal_load((const f32x4*)(kernb + p0));
    E0 = __builtin_nontemporal_load((const f32x4*)(embb + p0));
    E1 = __builtin_nontemporal_load((const f32x4*)(embb + (size_t)N + p0));
    E2 = __builtin_nontemporal_load((const f32x4*)(embb + (size_t)2 * N + p0));
    E3 = __builtin_nontemporal_load((const f32x4*)(embb + (size_t)3 * N + p0));
  }
  while (tile < tiles) {
    int4 lb;   // kern&&tm composed (for sums)
    int4 lt;   // tm-only composed (for pass2)
    lt.x = (T.x > 0.5f) ? (L.x & 31) : 0;
    lt.y = (T.y > 0.5f) ? (L.y & 31) : 0;
    lt.z = (T.z > 0.5f) ? (L.z & 31) : 0;
    lt.w = (T.w > 0.5f) ? (L.w & 31) : 0;
    lb.x = (Kk.x > 0.5f) ? lt.x : 0;
    lb.y = (Kk.y > 0.5f) ? lt.y : 0;
    lb.z = (Kk.z > 0.5f) ? lt.z : 0;
    lb.w = (Kk.w > 0.5f) ? lt.w : 0;
    *(int4*)&s_lab[w][lane * 4] = lb;
    unsigned packed = (unsigned)lt.x | ((unsigned)lt.y << 8) |
                      ((unsigned)lt.z << 16) | ((unsigned)lt.w << 24);
    __builtin_nontemporal_store(packed, &labg[(tile << 6) + lane]);

    uint2 r;
    r.x = pkrtz(E0.x, E0.y); r.y = pkrtz(E0.z, E0.w);
    *(uint2*)&s_embh[w][0 * EPAD + lane * 4] = r;
    r.x = pkrtz(E1.x, E1.y); r.y = pkrtz(E1.z, E1.w);
    *(uint2*)&s_embh[w][1 * EPAD + lane * 4] = r;
    r.x = pkrtz(E2.x, E2.y); r.y = pkrtz(E2.z, E2.w);
    *(uint2*)&s_embh[w][2 * EPAD + lane * 4] = r;
    r.x = pkrtz(E3.x, E3.y); r.y = pkrtz(E3.z, E3.w);
    *(uint2*)&s_embh[w][3 * EPAD + lane * 4] = r;

    const int next = tile + waves_total;
    if (next < tiles) {                      // prefetch next tile into regs
      const int p0 = (next << 8) + lane * 4;
      L  = __builtin_nontemporal_load((const i32x4*)(instb + p0));
      T  = __builtin_nontemporal_load((const f32x4*)(tmb + p0));
      Kk = __builtin_nontemporal_load((const f32x4*)(kernb + p0));
      E0 = __builtin_nontemporal_load((const f32x4*)(embb + p0));
      E1 = __builtin_nontemporal_load((const f32x4*)(embb + (size_t)N + p0));
      E2 = __builtin_nontemporal_load((const f32x4*)(embb + (size_t)2 * N + p0));
      E3 = __builtin_nontemporal_load((const f32x4*)(embb + (size_t)3 * N + p0));
    }
#pragma unroll
    for (int j = 0; j < 8; ++j) {
      const int p8 = j * 32 + g * 8;
      const int4 l0 = *(const int4*)&s_lab[w][p8];
      const int4 l1 = *(const int4*)&s_lab[w][p8 + 4];
      hfrag fa0, fa1, fb;
      fa0.u[0] = ohpair16(l0.x, l0.y, c);
      fa0.u[1] = ohpair16(l0.z, l0.w, c);
      fa0.u[2] = ohpair16(l1.x, l1.y, c);
      fa0.u[3] = ohpair16(l1.z, l1.w, c);
      fa1.u[0] = ohpair16(l0.x, l0.y, c + 16);
      fa1.u[1] = ohpair16(l0.z, l0.w, c + 16);
      fa1.u[2] = ohpair16(l1.x, l1.y, c + 16);
      fa1.u[3] = ohpair16(l1.z, l1.w, c + 16);
      if (c < 4) {
        fb.v = *(const half8*)&s_embh[w][c * EPAD + p8];
      } else if (c == 4) {
        fb.u[0] = fb.u[1] = fb.u[2] = fb.u[3] = 0x3C003C00u;  // col4 = 1.0
      } else {
        fb.u[0] = fb.u[1] = fb.u[2] = fb.u[3] = 0u;
      }
      acc0 = __builtin_amdgcn_mfma_f32_16x16x32_f16(fa0.v, fb.v, acc0, 0, 0, 0);
      acc1 = __builtin_amdgcn_mfma_f32_16x16x32_f16(fa1.v, fb.v, acc1, 0, 0, 0);
    }
    tile = next;
  }

  if (c < 5) {
#pragma unroll
    for (int jj = 0; jj < 4; ++jj) {
      const int row = g * 4 + jj;
      atomicAdd(&s_acc[row * 5 + c], acc0[jj]);
      atomicAdd(&s_acc[(16 + row) * 5 + c], acc1[jj]);
    }
  }
  if ((N & 255) != 0 && blockIdx.x == 0) {    // generic tail (dead at 640x640)
    for (int i = ((N >> 8) << 8) + t; i < N; i += 256) {
      int li = instb[i] & 31;
      bool tm_ok = tmb[i] > 0.5f;
      int lab = (tm_ok && kernb[i] > 0.5f) ? li : 0;
      atomicAdd(&gout[32 + lab], 1.f);
      atomicAdd(&gout[64 + lab],  embb[i]);
      atomicAdd(&gout[96 + lab],  embb[(size_t)N + i]);
      atomicAdd(&gout[128 + lab], embb[(size_t)2 * N + i]);
      atomicAdd(&gout[160 + lab], embb[(size_t)3 * N + i]);
      ((unsigned char*)lab8w)[off + i] = (unsigned char)(tm_ok ? li : 0);
    }
  }
  __syncthreads();
  if (t < 160) {
    float v = s_acc[t];
    if (v != 0.f) {
      const int row = t / 5, cc = t % 5;
      if (cc < 4) atomicAdd(&gout[64 + cc * 32 + row], v);
      else        atomicAdd(&gout[32 + row], v);
    }
  }
}

// ------- pass2: full-NT streaming over emb + lab8 mirror -------------------
__global__ __launch_bounds__(256)
void pass2_kernel(const float* __restrict__ emb, const unsigned* __restrict__ lab8w,
                  const float* __restrict__ maxd,
                  float* __restrict__ ws, int N, int B, int bpb)
{
  const int b = blockIdx.y;
  const int t = threadIdx.x;
  const int lane = t & 63, w = t >> 6;
  const int c = lane & 15, g = lane >> 4;
  __shared__ int s_lab[4][256];
  __shared__ __align__(16) unsigned short s_val[4][256];
  __shared__ __align__(16) float4 s_meanv[KI];
  __shared__ float s_scal[KI];
  __shared__ float s_acc[64];   // [0..31] valsum, [32..63] cnt
  float* gacc = ws + (size_t)b * 224;
  if (t < KI) {
    float inv = (t == 0) ? 0.f : 1.0f / fmaxf(gacc[32 + t], 1.0f);
    float4 m;
    m.x = gacc[64 + t]  * inv;
    m.y = gacc[96 + t]  * inv;
    m.z = gacc[128 + t] * inv;
    m.w = gacc[160 + t] * inv;
    s_meanv[t] = m;
    s_scal[t] = expf(maxd[b * KI + t]);
  }
  for (int i = t; i < 64; i += 256) s_acc[i] = 0.f;
  __syncthreads();

  const size_t off = (size_t)b * N;
  const unsigned* labp = lab8w + (off >> 2);
  const float* embb  = emb + (size_t)b * 4 * N;

  f32x4 acc0 = {0.f, 0.f, 0.f, 0.f};
  f32x4 acc1 = {0.f, 0.f, 0.f, 0.f};
  const int waves_total = bpb * 4;
  const int wave_id = blockIdx.x * 4 + w;
  const int tiles = N >> 8;

  int tile = wave_id;
  unsigned LT; f32x4 E0, E1, E2, E3;
  if (tile < tiles) {
    const int p0 = (tile << 8) + lane * 4;
    LT = __builtin_nontemporal_load(&labp[(tile << 6) + lane]);
    E0 = __builtin_nontemporal_load((const f32x4*)(embb + p0));
    E1 = __builtin_nontemporal_load((const f32x4*)(embb + (size_t)N + p0));
    E2 = __builtin_nontemporal_load((const f32x4*)(embb + (size_t)2 * N + p0));
    E3 = __builtin_nontemporal_load((const f32x4*)(embb + (size_t)3 * N + p0));
  }
  while (tile < tiles) {
    int4 lb;
    lb.x = (int)(LT & 31u);
    lb.y = (int)((LT >> 8) & 31u);
    lb.z = (int)((LT >> 16) & 31u);
    lb.w = (int)((LT >> 24) & 31u);
    *(int4*)&s_lab[w][lane * 4] = lb;
    float v0, v1, v2, v3;
#define VALC(res, li, a0, a1, a2, a3) {                                  \
      float4 mn = s_meanv[li];                                           \
      float sc = s_scal[li];                                             \
      float d0 = (a0) - mn.x, d1 = (a1) - mn.y;                          \
      float d2 = (a2) - mn.z, d3 = (a3) - mn.w;                          \
      float dd = sqrtf(d0 * d0 + d1 * d1 + d2 * d2 + d3 * d3);           \
      float aa = fmaxf(sc * dd - 0.5f, 0.f);                             \
      res = __logf(aa * aa + 1.f); }
    VALC(v0, lb.x, E0.x, E1.x, E2.x, E3.x)
    VALC(v1, lb.y, E0.y, E1.y, E2.y, E3.y)
    VALC(v2, lb.z, E0.z, E1.z, E2.z, E3.z)
    VALC(v3, lb.w, E0.w, E1.w, E2.w, E3.w)
#undef VALC
    uint2 vr;
    vr.x = pkrtz(v0, v1); vr.y = pkrtz(v2, v3);
    *(uint2*)&s_val[w][lane * 4] = vr;

    const int next = tile + waves_total;
    if (next < tiles) {
      const int p0 = (next << 8) + lane * 4;
      LT = __builtin_nontemporal_load(&labp[(next << 6) + lane]);
      E0 = __builtin_nontemporal_load((const f32x4*)(embb + p0));
      E1 = __builtin_nontemporal_load((const f32x4*)(embb + (size_t)N + p0));
      E2 = __builtin_nontemporal_load((const f32x4*)(embb + (size_t)2 * N + p0));
      E3 = __builtin_nontemporal_load((const f32x4*)(embb + (size_t)3 * N + p0));
    }
#pragma unroll
    for (int j = 0; j < 8; ++j) {
      const int p8 = j * 32 + g * 8;
      const int4 l0 = *(const int4*)&s_lab[w][p8];
      const int4 l1 = *(const int4*)&s_lab[w][p8 + 4];
      hfrag fa0, fa1, fb;
      fa0.u[0] = ohpair16(l0.x, l0.y, c);
      fa0.u[1] = ohpair16(l0.z, l0.w, c);
      fa0.u[2] = ohpair16(l1.x, l1.y, c);
      fa0.u[3] = ohpair16(l1.z, l1.w, c);
      fa1.u[0] = ohpair16(l0.x, l0.y, c + 16);
      fa1.u[1] = ohpair16(l0.z, l0.w, c + 16);
      fa1.u[2] = ohpair16(l1.x, l1.y, c + 16);
      fa1.u[3] = ohpair16(l1.z, l1.w, c + 16);
      if (c == 0) {
        fb.v = *(const half8*)&s_val[w][p8];
      } else if (c == 1) {
        fb.u[0] = fb.u[1] = fb.u[2] = fb.u[3] = 0x3C003C00u;  // col1 = 1.0
      } else {
        fb.u[0] = fb.u[1] = fb.u[2] = fb.u[3] = 0u;
      }
      acc0 = __builtin_amdgcn_mfma_f32_16x16x32_f16(fa0.v, fb.v, acc0, 0, 0, 0);
      acc1 = __builtin_amdgcn_mfma_f32_16x16x32_f16(fa1.v, fb.v, acc1, 0, 0, 0);
    }
    tile = next;
  }

  if (c < 2) {
#pragma unroll
    for (int jj = 0; jj < 4; ++jj) {
      const int row = g * 4 + jj;
      atomicAdd(&s_acc[c * 32 + row], acc0[jj]);
      atomicAdd(&s_acc[c * 32 + 16 + row], acc1[jj]);
    }
  }
  if ((N & 255) != 0 && blockIdx.x == 0) {    // generic tail (dead here)
    for (int i = ((N >> 8) << 8) + t; i < N; i += 256) {
      int lab = ((const unsigned char*)lab8w)[off + i] & 31;
      float4 mn = s_meanv[lab];
      float sc = s_scal[lab];
      float d0 = embb[i] - mn.x;
      float d1 = embb[(size_t)N + i] - mn.y;
      float d2 = embb[(size_t)2 * N + i] - mn.z;
      float d3 = embb[(size_t)3 * N + i] - mn.w;
      float dd = sqrtf(d0 * d0 + d1 * d1 + d2 * d2 + d3 * d3);
      float aa = fmaxf(sc * dd - 0.5f, 0.f);
      atomicAdd(&gacc[192 + lab], __logf(aa * aa + 1.f));
      atomicAdd(&gacc[lab], 1.f);
    }
  }
  __syncthreads();
  if (t < 64) {
    float v = s_acc[t];
    if (v != 0.f) {
      if (t < 32) atomicAdd(&gacc[192 + t], v);   // valsum
      else        atomicAdd(&gacc[t - 32], v);    // cnt
    }
  }
}

// ------------- bg_kernel: means + pairwise + l_reg + bg term ---------------
__global__ __launch_bounds__(256)
void bg_kernel(const float* __restrict__ emb, const int* __restrict__ inst,
               const float* __restrict__ tmask, float* __restrict__ ws, int N, int B)
{
  const int b = blockIdx.x;
  const int t = threadIdx.x;
  const int lane = t & 63, wave = t >> 6;
  float* gacc = ws + (size_t)b * 224;
  __shared__ float mean[KI][4];
  __shared__ int s_bgidx[BG_SAMPLE];
  __shared__ int s_count;
  __shared__ int s_wcnt[4];
  if (t == 0) s_count = 0;
  if (t < KI) {
    float inv = (t == 0) ? 0.f : 1.0f / fmaxf(gacc[32 + t], 1.0f);
    mean[t][0] = gacc[64 + t]  * inv;
    mean[t][1] = gacc[96 + t]  * inv;
    mean[t][2] = gacc[128 + t] * inv;
    mean[t][3] = gacc[160 + t] * inv;
  }
  __syncthreads();
  const int*   instb = inst + (size_t)b * N;
  const float* tmb   = tmask + (size_t)b * N;

  for (int base = 0; base < N; base += 256) {
    if (s_count >= BG_SAMPLE) break;
    int i = base + t;
    bool p = false;
    if (i < N) {
      int lab = instb[i];
      if (tmb[i] <= 0.5f) lab = 0;
      p = (lab == 0);
    }
    unsigned long long m = __ballot(p);
    if (lane == 0) s_wcnt[wave] = __popcll(m);
    __syncthreads();
    int pos = s_count;
    for (int ww = 0; ww < wave; ++ww) pos += s_wcnt[ww];
    if (p) {
      pos += __popcll(m & ((1ull << lane) - 1ull));
      if (pos < BG_SAMPLE) s_bgidx[pos] = i;
    }
    __syncthreads();
    if (t == 0) s_count += s_wcnt[0] + s_wcnt[1] + s_wcnt[2] + s_wcnt[3];
    __syncthreads();
  }
  if (s_count < BG_SAMPLE) {   // stable-argsort fallback: first non-bg indices
    for (int base = 0; base < N; base += 256) {
      if (s_count >= BG_SAMPLE) break;
      int i = base + t;
      bool p = false;
      if (i < N) {
        int lab = instb[i];
        if (tmb[i] <= 0.5f) lab = 0;
        p = (lab != 0);
      }
      unsigned long long m = __ballot(p);
      if (lane == 0) s_wcnt[wave] = __popcll(m);
      __syncthreads();
      int pos = s_count;
      for (int ww = 0; ww < wave; ++ww) pos += s_wcnt[ww];
      if (p) {
        pos += __popcll(m & ((1ull << lane) - 1ull));
        if (pos < BG_SAMPLE) s_bgidx[pos] = i;
      }
      __syncthreads();
      if (t == 0) s_count += s_wcnt[0] + s_wcnt[1] + s_wcnt[2] + s_wcnt[3];
      __syncthreads();
    }
  }
  __syncthreads();

  __shared__ float ebg[BG_SAMPLE][4];
  const float* embb = emb + (size_t)b * 4 * N;
  for (int j = t; j < BG_SAMPLE; j += 256) {
    int i = s_bgidx[j];
    ebg[j][0] = embb[i];
    ebg[j][1] = embb[(size_t)N + i];
    ebg[j][2] = embb[(size_t)2 * N + i];
    ebg[j][3] = embb[(size_t)3 * N + i];
  }
  __syncthreads();

  const float coef = 1.0f - expf(-10.0f / 32.0f);
  float lp = 0.f;
  for (int idx = t; idx < 31 * 31; idx += 256) {
    int i = 1 + idx / 31, j = 1 + idx % 31;
    if (i == j) continue;
    float d0 = mean[i][0] - mean[j][0];
    float d1 = mean[i][1] - mean[j][1];
    float d2 = mean[i][2] - mean[j][2];
    float d3 = mean[i][3] - mean[j][3];
    float pd = sqrtf(d0 * d0 + d1 * d1 + d2 * d2 + d3 * d3);
    float a = fmaxf(3.0f - coef * pd, 0.f);
    lp += logf(a * a + 1.f);
  }
  float lr = 0.f;
  for (int k = t; k < KI; k += 256) {
    float n = sqrtf(mean[k][0] * mean[k][0] + mean[k][1] * mean[k][1] +
                    mean[k][2] * mean[k][2] + mean[k][3] * mean[k][3]);
    lr += logf(n + 1.f);
  }
  float lbg = 0.f;
  for (int idx = t; idx < 31 * BG_SAMPLE; idx += 256) {
    int k = 1 + idx / BG_SAMPLE, j = idx % BG_SAMPLE;
    float d0 = ebg[j][0] - mean[k][0];
    float d1 = ebg[j][1] - mean[k][1];
    float d2 = ebg[j][2] - mean[k][2];
    float d3 = ebg[j][3] - mean[k][3];
    float dd = sqrtf(d0 * d0 + d1 * d1 + d2 * d2 + d3 * d3);
    float a = fmaxf(3.0f - coef * dd, 0.f);
    lbg += logf(a * a + 1.f);
  }
  float a0 = waveReduceSum(lp);
  float a1 = waveReduceSum(lr);
  float a2 = waveReduceSum(lbg);
  __shared__ float red[3][4];
  if (lane == 0) { red[0][wave] = a0; red[1][wave] = a1; red[2][wave] = a2; }
  __syncthreads();
  if (t == 0) {
    float* gmisc = ws + (size_t)B * 224 + (size_t)B * 128 + (size_t)b * 4;
    gmisc[0] = red[0][0] + red[0][1] + red[0][2] + red[0][3];
    gmisc[1] = (red[1][0] + red[1][1] + red[1][2] + red[1][3]) * (0.001f / 32.0f);
    gmisc[2] = (red[2][0] + red[2][1] + red[2][2] + red[2][3]) * (1.0f / BG_SAMPLE);
  }
}

__global__ __launch_bounds__(64)
void final_kernel(const float* __restrict__ ws, float* __restrict__ out, int B)
{
  const int t = threadIdx.x;
  __shared__ float s[64];
  float tot = 0.f;
  if (t < B) {
    const float* gacc  = ws + (size_t)t * 224;
    const float* gmisc = ws + (size_t)B * 224 + (size_t)B * 128 + (size_t)t * 4;
    float lagg = 0.f;
    for (int k = 1; k < KI; ++k)
      lagg += gacc[192 + k] / fmaxf(gacc[k], 1.0f);
    lagg *= (1.0f / 31.0f);
    float ldis = (gmisc[0] + gmisc[2]) * (1.0f / 961.0f);  // (K-1)(K-2)+(K-1)
    tot = lagg + ldis + gmisc[1];
  }
  s[t] = tot;
  __syncthreads();
  if (t == 0) {
    float sum = 0.f;
    for (int b = 0; b < B; ++b) sum += s[b];
    out[0] = sum / (float)B;
  }
}

extern "C" void kernel_launch(void* const* d_in, const int* in_sizes, int n_in,
                              void* d_out, int out_size, void* d_ws, size_t ws_size,
                              hipStream_t stream)
{
  const float* emb   = (const float*)d_in[0];
  const int*   inst  = (const int*)d_in[1];
  const float* kern  = (const float*)d_in[2];
  const float* tmask = (const float*)d_in[3];
  const float* maxd  = (const float*)d_in[5];
  float* out = (float*)d_out;
  float* ws  = (float*)d_ws;

  const int B = in_sizes[5] / KI;          // 16
  const int N = in_sizes[1] / B;           // 409600
  const int bpb = 100;                     // 400 waves/batch, 4 tiles each

  const size_t accFloats = (size_t)B * 356;
  unsigned* lab8w = (unsigned*)(ws + accFloats);
  const size_t need = accFloats * 4 + (size_t)B * N;
  if (ws_size < need) return;

  hipMemsetAsync(d_ws, 0, accFloats * 4, stream);
  pass1_kernel<<<dim3(bpb, B), 256, 0, stream>>>(emb, inst, kern, tmask, ws, lab8w, N, bpb);
  pass2_kernel<<<dim3(bpb, B), 256, 0, stream>>>(emb, lab8w, maxd, ws, N, B, bpb);
  bg_kernel<<<B, 256, 0, stream>>>(emb, inst, tmask, ws, N, B);
  final_kernel<<<1, 64, 0, stream>>>(ws, out, B);
}